// Round 7
// baseline (822.675 us; speedup 1.0000x reference)
//
#include <hip/hip_runtime.h>

// All tensors float32. ws poisoned each iteration; layout below ~7.5 MB.
// ws layout (float offsets):
#define OFF_SPP   0         // sp partials: [c<16][t<12][col<256]      (49152)
#define OFF_TPH   49152     // tp hidden (post-relu), 256
#define OFF_P1    65536     // fc1 partials: [(t*2048+col)*64+p]       (262144)
#define OFF_P2    327680    // fc2 partials: [(t*2048+col)*32+p]       (131072)
#define OFF_X     458752    // X_raw [t<2][12288], init fc_b3, atomic  (24576)
#define OFF_UP    524288    // U partials:  [y<32][ap<3][n<1024][t<12] (1179648)
#define OFF_TPP   1703936   // tp2 partials:[y<32][n<1024][ap<3]       (98304)
#define OFF_U     1802240   // U final [ap][n][t] (36864)
#define OFF_BAR   1839104   // barrier state: 3 x 32 ints (zeroed by k_init)

// ---------------------------------------------------------------------------
// 2-row GEMM body, split-K. Input is either direct (PIN==0), a gather from
// obs (GATHER==1), or the sum of PIN partials (+bias+relu). Output: plain
// partial store (ATOM==0) or device-scope atomicAdd into a pre-initialized
// accumulator (ATOM==1, P ignored).
template<int KS, int PIN, int P, int GATHER, int ATOM>
__device__ __forceinline__ void gemm_body(
    const float* __restrict__ xin, const float* __restrict__ bias_in,
    const float* __restrict__ W, float* __restrict__ part,
    int N, int K, int bx, int by, float* lx, float* red)
{
  int tid = threadIdx.x;
  int k0 = by * KS;
  for (int i = tid; i < 2*KS; i += 256) {
    int t = i / KS, kk = i - t*KS;
    float v;
    if (GATHER) {
      int k = k0 + kk;                      // col of (12 x 8192) obs matrix
      v = xin[(k >> 3)*96 + (k & 7)*12 + 9 + t];  // rows t=9,10 only
    } else if (PIN == 0) {
      v = xin[t*K + k0 + kk];
    } else {
      v = 0.f;
      const float* p0 = xin + (size_t)(t*K + k0 + kk)*PIN;
      #pragma unroll
      for (int pp = 0; pp < PIN; ++pp) v += p0[pp];
    }
    if (bias_in) { v += bias_in[k0 + kk]; v = v > 0.f ? v : 0.f; }
    lx[i] = v;
  }
  __syncthreads();
  int kg = tid >> 5, cg2 = tid & 31;
  int colbase = bx*128 + cg2*4;
  float a0=0,a1=0,a2=0,a3=0,c0=0,c1=0,c2=0,c3=0;
  const int ksub = KS/8;
  for (int kk = kg*ksub; kk < kg*ksub + ksub; ++kk) {
    float4 w = *(const float4*)(W + (size_t)(k0+kk)*N + colbase);
    float x0 = lx[kk], x1 = lx[KS + kk];
    a0=fmaf(x0,w.x,a0); a1=fmaf(x0,w.y,a1); a2=fmaf(x0,w.z,a2); a3=fmaf(x0,w.w,a3);
    c0=fmaf(x1,w.x,c0); c1=fmaf(x1,w.y,c1); c2=fmaf(x1,w.z,c2); c3=fmaf(x1,w.w,c3);
  }
  float* rp = red + (kg*32 + cg2)*8;
  rp[0]=a0; rp[1]=a1; rp[2]=a2; rp[3]=a3; rp[4]=c0; rp[5]=c1; rp[6]=c2; rp[7]=c3;
  __syncthreads();
  int cg3 = tid & 31, q = tid >> 5;
  float s = 0.f;
  #pragma unroll
  for (int g = 0; g < 8; ++g) s += red[(g*32 + cg3)*8 + q];
  int t = q >> 2, c = q & 3;
  if (ATOM) {
    atomicAdd(part + (size_t)t*N + bx*128 + cg3*4 + c, s);
  } else {
    part[(size_t)(t*N + bx*128 + cg3*4 + c)*P + by] = s;
  }
}

// ---------------------------------------------------------------------------
// Grid barrier (one-shot, 3 instances). Two-level arrive (8 leaves of 128
// blocks -> root), release via flag on its own cacheline. Safe because all
// 1024 blocks are co-resident by construction (__launch_bounds__(256,4):
// VGPR<=128, LDS 27.8KB*4=111KB<=160KB, 16 waves<=32 per CU). Timeout valve:
// if residency assumption ever breaks we produce garbage (test fails) rather
// than hanging the container.
__device__ __forceinline__ void gbar(int* bs, int idx)
{
  __syncthreads();
  if (threadIdx.x == 0) {
    int* leaf = bs + idx*32;       // 8 counters
    int* root = leaf + 8;
    int* flag = leaf + 16;         // separate 64B line
    __threadfence();
    int li = (blockIdx.x >> 7) & 7;
    if (atomicAdd(&leaf[li], 1) == 127) {
      if (atomicAdd(root, 1) == 7) {
        __hip_atomic_store(flag, 1, __ATOMIC_RELEASE, __HIP_MEMORY_SCOPE_AGENT);
      }
    }
    int spins = 0;
    while (__hip_atomic_load(flag, __ATOMIC_ACQUIRE,
                             __HIP_MEMORY_SCOPE_AGENT) == 0) {
      __builtin_amdgcn_s_sleep(2);
      if (++spins > (1 << 22)) break;     // ~0.5s: garbage > hang
    }
    __threadfence();
  }
  __syncthreads();
}

// ---------------------------------------------------------------------------
// k_init (33 blocks): sp first-layer partials (16) | tp hidden + barrier
// zero (1) | X_raw=fc_b3 init + zero out[1..3] (16).
__global__ void __launch_bounds__(256) k_init(
    const float* __restrict__ li, const float* __restrict__ gs_w1,
    const float* __restrict__ tf, const float* __restrict__ gt_w1,
    const float* __restrict__ gt_b1, const float* __restrict__ fc_b3,
    float* __restrict__ sp_part, float* __restrict__ tp_h,
    float* __restrict__ X_raw, float* __restrict__ out_tail,
    int* __restrict__ bs)
{
  __shared__ float lil[12][128];
  int b = blockIdx.x, tid = threadIdx.x;
  if (b < 16) {
    int cb = b & 1, kc = b >> 1;            // col chunk (128), k chunk (128)
    for (int i = tid; i < 1536; i += 256) {
      int r = i >> 7, kk = i & 127;
      lil[r][kk] = li[r*1024 + kc*128 + kk];
    }
    __syncthreads();
    int col = cb*128 + (tid & 127);
    int kh = tid >> 7;                      // k-half of 64
    float acc[12];
    #pragma unroll
    for (int t=0;t<12;++t) acc[t]=0.f;
    for (int kk = kh*64; kk < kh*64 + 64; ++kk) {
      float w = gs_w1[(size_t)(kc*128 + kk)*256 + col];
      #pragma unroll
      for (int t=0;t<12;++t) acc[t] = fmaf(lil[t][kk], w, acc[t]);
    }
    int c = kc*2 + kh;                      // 0..15 partial chunk
    #pragma unroll
    for (int t=0;t<12;++t) sp_part[(c*12 + t)*256 + col] = acc[t];
  } else if (b == 16) {
    if (tid < 96) bs[tid] = 0;              // 3 x 32-int barrier instances
    float acc = 0.f;
    for (int k = 0; k < 36; ++k)
      acc = fmaf(tf[k], gt_w1[k*256 + tid], acc);
    float v = acc + gt_b1[tid];
    tp_h[tid] = v > 0.f ? v : 0.f;
  } else {
    int sb = b - 17;                        // 0..15
    for (int i = tid; i < 1536; i += 256) { // X_raw[2][12288] = fc_b3
      int idx = sb*1536 + i;
      int colx = idx >= 12288 ? idx - 12288 : idx;
      X_raw[idx] = fc_b3[colx];
    }
    for (int i = tid; i < 2304; i += 256)   // zero outputs 1..3
      out_tail[sb*2304 + i] = 0.f;
  }
}

// ---------------------------------------------------------------------------
// k_mega (1024 blocks, all co-resident):
// P0: fc1 (1024, split-K 64x128, obs gathered in staging)
// P1: fc2 (512, split-K 32x64) || split-K U-GEMM (128)
// P2: fc3 (768, split-K 8x256, atomicAdd into X_raw) || U finalize (144)
// P3: fused scores/softmax/weighted-sum/epilogue (512)
#define SS 1032
__global__ void __launch_bounds__(256, 4) k_mega(
    const float* __restrict__ obs, const float* __restrict__ fc_w1,
    float* __restrict__ part1, const float* __restrict__ fc_b1,
    const float* __restrict__ fc_w2, float* __restrict__ part2,
    const float* __restrict__ fc_b2, const float* __restrict__ fc_w3,
    float* __restrict__ X_raw,
    const float* __restrict__ sp_part, const float* __restrict__ gs_b1,
    const float* __restrict__ tp_h,
    const float* __restrict__ gs_w2, const float* __restrict__ gt_w2,
    float* __restrict__ U_part, float* __restrict__ tp_part,
    const float* __restrict__ gs_b2, const float* __restrict__ gt_b2,
    float* __restrict__ U, const float* __restrict__ Bm,
    const float* __restrict__ Wf, const float* __restrict__ Wb,
    const float* __restrict__ bvec, float* __restrict__ out,
    int* __restrict__ bs)
{
  __shared__ float smem[6944];
  int b = blockIdx.x, tid = threadIdx.x;

  // ===== P0: fc1 =====
  gemm_body<128, 0, 64, 1, 0>(obs, (const float*)nullptr, fc_w1, part1,
                              2048, 8192, b & 15, b >> 4, smem, smem + 256);
  gbar(bs, 0);

  // ===== P1: fc2 || U-GEMM =====
  if (b < 512) {
    gemm_body<64, 64, 32, 0, 0>(part1, fc_b1, fc_w2, part2, 2048, 2048,
                                b & 15, b >> 4, smem, smem + 128);
  } else if (b < 640) {
    float* spl = smem;        // 96: relu'd sp hidden [kk<8][t<12]
    float* tpl = smem + 96;   // 8
    int ug = b - 512;
    int n  = (ug & 3)*256 + tid;
    int uy = ug >> 2;
    int k0 = uy*8;
    if (tid < 96) {
      int kk = tid / 12, t = tid % 12;
      float v = gs_b1[k0 + kk];
      #pragma unroll
      for (int c = 0; c < 16; ++c) v += sp_part[(c*12 + t)*256 + k0 + kk];
      spl[kk*12 + t] = v > 0.f ? v : 0.f;
    }
    if (tid < 8) tpl[tid] = tp_h[k0 + tid];
    __syncthreads();
    float sA[3][12];
    float tA[3] = {0.f, 0.f, 0.f};
    #pragma unroll
    for (int ap=0;ap<3;++ap)
      #pragma unroll
      for (int t=0;t<12;++t) sA[ap][t]=0.f;
    #pragma unroll
    for (int kk = 0; kk < 8; ++kk) {
      float4 ws4 = *(const float4*)(gs_w2 + (size_t)(k0+kk)*12288 + 12*n + 8);
      float4 wt4 = *(const float4*)(gt_w2 + (size_t)(k0+kk)*12288 + 12*n + 8);
      float w0 = ws4.y, w1 = ws4.z, w2 = ws4.w;
      #pragma unroll
      for (int t=0;t<12;++t) {
        float s = spl[kk*12 + t];
        sA[0][t] = fmaf(s, w0, sA[0][t]);
        sA[1][t] = fmaf(s, w1, sA[1][t]);
        sA[2][t] = fmaf(s, w2, sA[2][t]);
      }
      float tv = tpl[kk];
      tA[0] = fmaf(tv, wt4.y, tA[0]);
      tA[1] = fmaf(tv, wt4.z, tA[1]);
      tA[2] = fmaf(tv, wt4.w, tA[2]);
    }
    #pragma unroll
    for (int ap=0;ap<3;++ap) {
      #pragma unroll
      for (int t=0;t<12;++t)
        U_part[(size_t)uy*36864 + ap*12288 + n*12 + t] = sA[ap][t];
      tp_part[uy*3072 + n*3 + ap] = tA[ap];
    }
  }
  gbar(bs, 1);

  // ===== P2: fc3 (atomic) || U finalize =====
  if (b < 768) {
    int by = b / 96, bx = b - by*96;
    gemm_body<256, 32, 0, 0, 1>(part2, fc_b2, fc_w3, X_raw, 12288, 2048,
                                bx, by, smem, smem + 512);
  } else if (b < 912) {
    int i = (b - 768)*256 + tid;            // < 36864
    float us = 0.f;
    for (int y = 0; y < 32; ++y) us += U_part[(size_t)y*36864 + i];
    int ap = i / 12288, rem = i - ap*12288, n = rem / 12;
    float ts = 0.f;
    for (int y = 0; y < 32; ++y) ts += tp_part[y*3072 + n*3 + ap];
    int c = n*12 + 9 + ap;
    float sv = us + gs_b2[c]; sv = sv > 0.f ? sv : 0.f;
    float tv = ts + gt_b2[c]; tv = tv > 0.f ? tv : 0.f;
    U[i] = sv + tv;
  }
  gbar(bs, 2);

  // ===== P3: scores -> softmax -> weighted X-sum -> Ws -> epilogue =====
  if (b < 512) {
    float* sc   = smem;            // 6*1032 = 6192
    float* Pm   = smem + 6192;     // 72
    float* invS = smem + 6264;     // 6 (pad to 6272)
    float* Bl   = smem + 6272;     // 144
    float* Ws0  = smem + 6416;     // 144
    float* Ws1  = smem + 6560;     // 144
    float* Ws2  = smem + 6704;     // 144
    float* wbuf = smem + 6848;     // 72
    float* bl   = smem + 6920;     // 12
    int i0 = b*2;
    if (tid < 144) {
      Bl[tid]  = Bm[tid];
      Ws0[tid] = Wf[144 + tid];          // Wf[1]       (path 0, L(9,10))
      Ws1[tid] = Wf[tid] + Wb[tid];      // Wf[0]+Wb[0] (path 1, L(10,10))
      Ws2[tid] = Wb[144 + tid];          // Wb[1]       (path 2, L(11,10))
    }
    if (tid < 12) bl[tid] = bvec[tid];
    __syncthreads();
    if (tid < 72) {
      int r = tid / 36, ap = (tid / 12) % 3, j = tid % 12;
      float s = 0.f;
      #pragma unroll
      for (int t=0;t<12;++t)
        s = fmaf(U[ap*12288 + (i0+r)*12 + t], Bl[t*12 + j], s);
      Pm[(r*3+ap)*12 + j] = s;
    }
    __syncthreads();
    const float* U10 = U + 12288;
    for (int jj = 0; jj < 4; ++jj) {
      int j = tid + jj*256;
      const float4* ur = (const float4*)(U10 + j*12);
      float4 u0 = ur[0], u1 = ur[1], u2 = ur[2];
      float u[12] = {u0.x,u0.y,u0.z,u0.w,u1.x,u1.y,u1.z,u1.w,u2.x,u2.y,u2.z,u2.w};
      #pragma unroll
      for (int r=0;r<2;++r)
        #pragma unroll
        for (int ap=0;ap<3;++ap) {
          float s = 0.f;
          #pragma unroll
          for (int t=0;t<12;++t) s = fmaf(Pm[(r*3+ap)*12 + t], u[t], s);
          sc[(r*3+ap)*SS + j] = (s >= 0.05f) ? s : 0.f;
        }
    }
    __syncthreads();
    int wv = tid >> 6, ln = tid & 63;
    for (int pr = wv; pr < 6; pr += 4) {
      float m = -1e30f;
      for (int q = 0; q < 16; ++q) m = fmaxf(m, sc[pr*SS + ln + q*64]);
      #pragma unroll
      for (int o = 32; o > 0; o >>= 1) m = fmaxf(m, __shfl_xor(m, o));
      float sum = 0.f;
      for (int q = 0; q < 16; ++q) {
        int j = ln + q*64;
        float e = __expf(sc[pr*SS + j] - m);
        sc[pr*SS + j] = e;
        sum += e;
      }
      #pragma unroll
      for (int o = 32; o > 0; o >>= 1) sum += __shfl_xor(sum, o);
      if (ln == 0) invS[pr] = 1.f / sum;
    }
    __syncthreads();
    float acc[2][12];
    #pragma unroll
    for (int r = 0; r < 2; ++r)
      #pragma unroll
      for (int f = 0; f < 12; ++f)
        acc[r][f] = 0.f;
    int q3 = tid >> 6, jg = tid & 63;
    if (tid < 192) {
      int row = (q3 == 1) ? 1 : 0;     // paths 0,2 use X9 (row 0); path 1 X10
      const float* xr = X_raw + (size_t)row*12288;
      for (int q = 0; q < 16; ++q) {
        int j = jg + q*64;
        float e0 = sc[q3*SS + j];          // pr = 0*3+q3
        float e1 = sc[(3 + q3)*SS + j];    // pr = 1*3+q3
        const float4* px = (const float4*)(xr + j*12);
        float4 v0 = px[0], v1 = px[1], v2 = px[2];
        float xv[12] = {v0.x,v0.y,v0.z,v0.w,v1.x,v1.y,v1.z,v1.w,
                        v2.x,v2.y,v2.z,v2.w};
        #pragma unroll
        for (int f = 0; f < 12; ++f) {
          float x = xv[f] > 0.f ? xv[f] : 0.f;
          acc[0][f] = fmaf(e0, x, acc[0][f]);
          acc[1][f] = fmaf(e1, x, acc[1][f]);
        }
      }
    }
    __syncthreads();
    float* red = sc;                   // sc values consumed; reuse as scratch
    if (tid < 192) {
      #pragma unroll
      for (int r=0;r<2;++r)
        #pragma unroll
        for (int f=0;f<12;++f)
          red[((q3*2 + r)*12 + f)*64 + jg] = acc[r][f];
    }
    __syncthreads();
    if (tid < 72) {
      int q3b = tid / 24, rr = (tid / 12) % 2, f = tid % 12;
      float s = 0.f;
      for (int g = 0; g < 64; ++g) s += red[((q3b*2 + rr)*12 + f)*64 + g];
      wbuf[(q3b*2 + rr)*12 + f] = s;
    }
    __syncthreads();
    if (tid < 24) {
      int r = tid / 12, g = tid % 12;
      float y0=0.f, y1=0.f, y2=0.f;
      #pragma unroll
      for (int f=0; f<12; ++f) {
        y0 = fmaf(wbuf[(0*2+r)*12+f], Ws0[f*12+g], y0);
        y1 = fmaf(wbuf[(1*2+r)*12+f], Ws1[f*12+g], y1);
        y2 = fmaf(wbuf[(2*2+r)*12+f], Ws2[f*12+g], y2);
      }
      float a1v = invS[r*3+1]*y1;
      float a2v = invS[r*3+0]*y0 + invS[r*3+2]*y2;
      float v1 = a1v + bl[g]; v1 = v1>0.f ? v1 : 0.f;
      float v2 = a2v + bl[g]; v2 = v2>0.f ? v2 : 0.f;
      out[(i0+r)*12 + g] = v1 + v2;
    }
  }
}

extern "C" void kernel_launch(void* const* d_in, const int* in_sizes, int n_in,
                              void* d_out, int out_size, void* d_ws, size_t ws_size,
                              hipStream_t stream)
{
  const float* obs   = (const float*)d_in[0];
  const float* tf    = (const float*)d_in[1];
  const float* fc_w1 = (const float*)d_in[2];
  const float* fc_b1 = (const float*)d_in[3];
  const float* fc_w2 = (const float*)d_in[4];
  const float* fc_b2 = (const float*)d_in[5];
  const float* fc_w3 = (const float*)d_in[6];
  const float* fc_b3 = (const float*)d_in[7];
  const float* Wf    = (const float*)d_in[8];
  const float* Wb    = (const float*)d_in[9];
  const float* bvec  = (const float*)d_in[10];
  const float* li    = (const float*)d_in[11];
  const float* gs_w1 = (const float*)d_in[12];
  const float* gs_b1 = (const float*)d_in[13];
  const float* gs_w2 = (const float*)d_in[14];
  const float* gs_b2 = (const float*)d_in[15];
  const float* gt_w1 = (const float*)d_in[16];
  const float* gt_b1 = (const float*)d_in[17];
  const float* gt_w2 = (const float*)d_in[18];
  const float* gt_b2 = (const float*)d_in[19];
  const float* Bm    = (const float*)d_in[20];
  float* out = (float*)d_out;
  float* ws  = (float*)d_ws;

  float* sp_part = ws + OFF_SPP;
  float* tp_h    = ws + OFF_TPH;
  float* part1   = ws + OFF_P1;
  float* part2   = ws + OFF_P2;
  float* X_raw   = ws + OFF_X;
  float* U_part  = ws + OFF_UP;
  float* tp_part = ws + OFF_TPP;
  float* U       = ws + OFF_U;
  int*   bs      = (int*)(ws + OFF_BAR);

  k_init<<<dim3(33), dim3(256), 0, stream>>>(li, gs_w1, tf, gt_w1, gt_b1,
                                             fc_b3, sp_part, tp_h, X_raw,
                                             out + 12288, bs);
  k_mega<<<dim3(1024), dim3(256), 0, stream>>>(obs, fc_w1, part1,
                                               fc_b1, fc_w2, part2,
                                               fc_b2, fc_w3, X_raw,
                                               sp_part, gs_b1, tp_h,
                                               gs_w2, gt_w2, U_part, tp_part,
                                               gs_b2, gt_b2, U, Bm,
                                               Wf, Wb, bvec, out, bs);
}